// Round 5
// baseline (157.393 us; speedup 1.0000x reference)
//
#include <hip/hip_runtime.h>

#define N_TOK 128
#define DIM   64
#define LN_EPS 1e-5f
#define SLOPE  0.01f

typedef float f32x4 __attribute__((ext_vector_type(4)));

__device__ __forceinline__ float wave_reduce_sum(float v) {
#pragma unroll
    for (int off = 32; off >= 1; off >>= 1) v += __shfl_xor(v, off, 64);
    return v;
}
__device__ __forceinline__ float wave_reduce_max(float v) {
#pragma unroll
    for (int off = 32; off >= 1; off >>= 1) v = fmaxf(v, __shfl_xor(v, off, 64));
    return v;
}

// DPP add step: v += dpp_perm(v). bound_ctrl=true -> out-of-row lanes add 0.
template<int CTRL>
__device__ __forceinline__ float dpp_add(float v) {
    int p = __builtin_amdgcn_update_dpp(0, __float_as_int(v), CTRL, 0xF, 0xF, true);
    return v + __int_as_float(p);
}
// Sum across each 16-lane row (VALU pipe only, no LDS/DS ops).
// After this, lanes 12..15 of each row hold the full 16-lane sum.
__device__ __forceinline__ float row16_sum(float v) {
    v = dpp_add<0xB1>(v);    // quad_perm [1,0,3,2] : + lane^1
    v = dpp_add<0x4E>(v);    // quad_perm [2,3,0,1] : + lane^2
    v = dpp_add<0x114>(v);   // row_shr:4
    v = dpp_add<0x118>(v);   // row_shr:8
    return v;
}

// ---------------------------------------------------------------------------
// K0: per-row LayerNorm stats -> q_score[b,n], k_score[b,n]  (LN folded)
// ---------------------------------------------------------------------------
__global__ __launch_bounds__(256) void k0_row_stats(
        const float* __restrict__ emb, const float* __restrict__ gamma,
        const float* __restrict__ beta, const float* __restrict__ attw,
        float* __restrict__ q_ws, float* __restrict__ k_ws, int nrows) {
    int wave = threadIdx.x >> 6, lane = threadIdx.x & 63;
    int r = blockIdx.x * 4 + wave;
    if (r >= nrows) return;
    float e  = emb[r * DIM + lane];
    float g  = gamma[lane], bt = beta[lane];
    float wq = attw[lane], wk = attw[DIM + lane];
    float gwq = g * wq, gwk = g * wk;

    float se  = wave_reduce_sum(e);
    float se2 = wave_reduce_sum(e * e);
    float sq  = wave_reduce_sum(e * gwq);
    float sk  = wave_reduce_sum(e * gwk);
    float Sgq = wave_reduce_sum(gwq);
    float Sbq = wave_reduce_sum(bt * wq);
    float Sgk = wave_reduce_sum(gwk);
    float Sbk = wave_reduce_sum(bt * wk);

    if (lane == 0) {
        float mu  = se * (1.f / 64.f);
        float var = se2 * (1.f / 64.f) - mu * mu;
        float rsq = rsqrtf(var + LN_EPS);
        q_ws[r] = rsq * (sq - mu * Sgq) + Sbq;
        k_ws[r] = rsq * (sk - mu * Sgk) + Sbk;
    }
}

// ---------------------------------------------------------------------------
// K12 (fused): one block per (b,i). Streams value[b,i,:,:] (32 KB, nt float4)
// and reduces the same register products into the 3 score sums via DPP
// (VALU pipe, zero DS ops in the hot loop). Leaders (c==15) stash the
// per-j sums in LDS; one finish wave does LN + leaky + softmax for all j.
// ---------------------------------------------------------------------------
__global__ __launch_bounds__(256) void k12_fused(
        const float* __restrict__ emb, const float* __restrict__ gamma,
        const float* __restrict__ beta, const float* __restrict__ attw,
        const float* __restrict__ attb, const float* __restrict__ q_ws,
        const float* __restrict__ k_ws, float* __restrict__ alphas,
        f32x4* __restrict__ value4) {
    __shared__ float2 s12v[N_TOK];   // (s1, s2) per j
    __shared__ float  s3a[N_TOK];    // s3 per j

    int b = blockIdx.x >> 7;
    int i = blockIdx.x & 127;
    int c  = threadIdx.x & 15;       // float4 chunk over d
    int jg = threadIdx.x >> 4;       // j-group 0..15

    const f32x4* E4 = (const f32x4*)emb + ((size_t)(b * N_TOK) << 4);
    f32x4 a4  = E4[(i << 4) | c];                          // e_i chunk
    f32x4 g4  = ((const f32x4*)gamma)[c];
    f32x4 wv4 = ((const f32x4*)(attw + 2 * DIM))[c];
    f32x4 gw  = g4 * wv4;

    f32x4* vrow = value4 + ((size_t)blockIdx.x << 11);     // 2048 float4 / row

#pragma unroll
    for (int it = 0; it < 8; ++it) {
        int j = (it << 4) | jg;
        f32x4 e4 = E4[(j << 4) | c];                       // L1/L2-hot
        f32x4 t4 = a4 * e4;
        __builtin_nontemporal_store(t4, &vrow[(j << 4) | c]);  // stream out

        float s1 = t4[0] + t4[1] + t4[2] + t4[3];
        float s2 = t4[0]*t4[0] + t4[1]*t4[1] + t4[2]*t4[2] + t4[3]*t4[3];
        float s3 = t4[0]*gw[0] + t4[1]*gw[1] + t4[2]*gw[2] + t4[3]*gw[3];
        s1 = row16_sum(s1);                                // VALU-only reduce
        s2 = row16_sum(s2);
        s3 = row16_sum(s3);
        if (c == 15) {                                     // row leader
            s12v[j] = make_float2(s1, s2);
            s3a[j]  = s3;
        }
    }
    __syncthreads();

    // Finish wave: LN(value)-score + q + k + bias, leaky, softmax over 128 j.
    if (threadIdx.x < 64) {
        int lane = threadIdx.x;
        float g = gamma[lane], bt = beta[lane], wv = attw[2 * DIM + lane];
        float Sg = wave_reduce_sum(g * wv);                // sum(gamma*wv)
        float Sb = wave_reduce_sum(bt * wv);               // sum(beta*wv)
        float qi = q_ws[b * N_TOK + i] + attb[0];

        float2 p0 = s12v[lane];
        float2 p1 = s12v[lane + 64];
        float s30 = s3a[lane], s31 = s3a[lane + 64];
        float kj0 = k_ws[b * N_TOK + lane];
        float kj1 = k_ws[b * N_TOK + lane + 64];

        float mu0  = p0.x * (1.f / 64.f);
        float var0 = p0.y * (1.f / 64.f) - mu0 * mu0;
        float sc0  = qi + kj0 + rsqrtf(var0 + LN_EPS) * (s30 - mu0 * Sg) + Sb;
        sc0 = sc0 >= 0.f ? sc0 : SLOPE * sc0;

        float mu1  = p1.x * (1.f / 64.f);
        float var1 = p1.y * (1.f / 64.f) - mu1 * mu1;
        float sc1  = qi + kj1 + rsqrtf(var1 + LN_EPS) * (s31 - mu1 * Sg) + Sb;
        sc1 = sc1 >= 0.f ? sc1 : SLOPE * sc1;

        float m  = wave_reduce_max(fmaxf(sc0, sc1));
        float e0 = __expf(sc0 - m), e1 = __expf(sc1 - m);
        float s  = wave_reduce_sum(e0 + e1);
        float inv = 1.f / s;
        float* arow = alphas + ((size_t)blockIdx.x << 7);
        arow[lane]      = e0 * inv;
        arow[lane + 64] = e1 * inv;
    }
}

extern "C" void kernel_launch(void* const* d_in, const int* in_sizes, int n_in,
                              void* d_out, int out_size, void* d_ws, size_t ws_size,
                              hipStream_t stream) {
    const float* emb   = (const float*)d_in[0];
    const float* gamma = (const float*)d_in[1];
    const float* beta  = (const float*)d_in[2];
    const float* attw  = (const float*)d_in[3];
    const float* attb  = (const float*)d_in[4];
    float* out = (float*)d_out;

    int B = in_sizes[0] / (N_TOK * DIM);     // 32
    int nrows = B * N_TOK;                   // 4096
    float* q_ws = (float*)d_ws;
    float* k_ws = q_ws + nrows;

    float* alphas = out;                             // B*N*N floats
    float* value  = out + (size_t)nrows * N_TOK;     // B*N*N*D floats

    k0_row_stats<<<dim3((nrows + 3) / 4), dim3(256), 0, stream>>>(
        emb, gamma, beta, attw, q_ws, k_ws, nrows);
    k12_fused<<<dim3(nrows), dim3(256), 0, stream>>>(
        emb, gamma, beta, attw, attb, q_ws, k_ws, alphas, (f32x4*)value);
}

// Round 6
// 151.335 us; speedup vs baseline: 1.0400x; 1.0400x over previous
//
#include <hip/hip_runtime.h>

#define N_TOK 128
#define DIM   64
#define LN_EPS 1e-5f
#define SLOPE  0.01f

typedef float f32x4 __attribute__((ext_vector_type(4)));

__device__ __forceinline__ float wave_reduce_sum(float v) {
#pragma unroll
    for (int off = 32; off >= 1; off >>= 1) v += __shfl_xor(v, off, 64);
    return v;
}
__device__ __forceinline__ float wave_reduce_max(float v) {
#pragma unroll
    for (int off = 32; off >= 1; off >>= 1) v = fmaxf(v, __shfl_xor(v, off, 64));
    return v;
}

// DPP add step: v += dpp_perm(v). bound_ctrl=true -> out-of-row lanes add 0.
template<int CTRL>
__device__ __forceinline__ float dpp_add(float v) {
    int p = __builtin_amdgcn_update_dpp(0, __float_as_int(v), CTRL, 0xF, 0xF, true);
    return v + __int_as_float(p);
}
// Sum across each 16-lane row (VALU pipe only, no DS ops).
// After this, lanes 12..15 of each row hold the full 16-lane sum.
__device__ __forceinline__ float row16_sum(float v) {
    v = dpp_add<0xB1>(v);    // quad_perm [1,0,3,2] : + lane^1
    v = dpp_add<0x4E>(v);    // quad_perm [2,3,0,1] : + lane^2
    v = dpp_add<0x114>(v);   // row_shr:4
    v = dpp_add<0x118>(v);   // row_shr:8
    return v;
}

// ---------------------------------------------------------------------------
// K0: per-row LayerNorm stats -> q_score[b,n], k_score[b,n]  (LN folded)
// ---------------------------------------------------------------------------
__global__ __launch_bounds__(256) void k0_row_stats(
        const float* __restrict__ emb, const float* __restrict__ gamma,
        const float* __restrict__ beta, const float* __restrict__ attw,
        float* __restrict__ q_ws, float* __restrict__ k_ws, int nrows) {
    int wave = threadIdx.x >> 6, lane = threadIdx.x & 63;
    int r = blockIdx.x * 4 + wave;
    if (r >= nrows) return;
    float e  = emb[r * DIM + lane];
    float g  = gamma[lane], bt = beta[lane];
    float wq = attw[lane], wk = attw[DIM + lane];
    float gwq = g * wq, gwk = g * wk;

    float se  = wave_reduce_sum(e);
    float se2 = wave_reduce_sum(e * e);
    float sq  = wave_reduce_sum(e * gwq);
    float sk  = wave_reduce_sum(e * gwk);
    float Sgq = wave_reduce_sum(gwq);
    float Sbq = wave_reduce_sum(bt * wq);
    float Sgk = wave_reduce_sum(gwk);
    float Sbk = wave_reduce_sum(bt * wk);

    if (lane == 0) {
        float mu  = se * (1.f / 64.f);
        float var = se2 * (1.f / 64.f) - mu * mu;
        float rsq = rsqrtf(var + LN_EPS);
        q_ws[r] = rsq * (sq - mu * Sgq) + Sbq;
        k_ws[r] = rsq * (sk - mu * Sgk) + Sbk;
    }
}

// ---------------------------------------------------------------------------
// K12 (fused, store-after-barrier): one block per (b,i).
// Phase 1: compute all t4 = e_i*e_j chunks into REGISTERS, DPP-reduce the
//          3 score sums, leaders stash per-j sums in LDS.
// Barrier:  only waits on (long-retired) loads + LDS — never on stores.
// Phase 2: issue the 32 KB of value stores; block exits with stores in
//          flight (no vmcnt(0) before s_endpgm) so the CU backfills the
//          next block while HBM drains. Softmax wave finishes alphas.
// ---------------------------------------------------------------------------
__global__ __launch_bounds__(256) void k12_fused(
        const float* __restrict__ emb, const float* __restrict__ gamma,
        const float* __restrict__ beta, const float* __restrict__ attw,
        const float* __restrict__ attb, const float* __restrict__ q_ws,
        const float* __restrict__ k_ws, float* __restrict__ alphas,
        f32x4* __restrict__ value4) {
    __shared__ float2 s12v[N_TOK];   // (s1, s2) per j
    __shared__ float  s3a[N_TOK];    // s3 per j

    int b = blockIdx.x >> 7;
    int i = blockIdx.x & 127;
    int c  = threadIdx.x & 15;       // float4 chunk over d
    int jg = threadIdx.x >> 4;       // j-group 0..15

    const f32x4* E4 = (const f32x4*)emb + ((size_t)(b * N_TOK) << 4);
    f32x4 a4  = E4[(i << 4) | c];                          // e_i chunk
    f32x4 g4  = ((const f32x4*)gamma)[c];
    f32x4 wv4 = ((const f32x4*)(attw + 2 * DIM))[c];
    f32x4 gw  = g4 * wv4;

    // ---- Phase 1: compute + reduce (no stores issued yet) ----
    f32x4 t[8];
#pragma unroll
    for (int it = 0; it < 8; ++it) {
        int j = (it << 4) | jg;
        f32x4 e4 = E4[(j << 4) | c];                       // L1/L2-hot
        t[it] = a4 * e4;

        float s1 = t[it][0] + t[it][1] + t[it][2] + t[it][3];
        float s2 = t[it][0]*t[it][0] + t[it][1]*t[it][1]
                 + t[it][2]*t[it][2] + t[it][3]*t[it][3];
        float s3 = t[it][0]*gw[0] + t[it][1]*gw[1]
                 + t[it][2]*gw[2] + t[it][3]*gw[3];
        s1 = row16_sum(s1);                                // VALU-only reduce
        s2 = row16_sum(s2);
        s3 = row16_sum(s3);
        if (c == 15) {                                     // row leader
            s12v[(it << 4) | jg] = make_float2(s1, s2);
            s3a[(it << 4) | jg]  = s3;
        }
    }
    __syncthreads();   // waits on loads (done) + LDS only — stores not issued

    // ---- Phase 2: stream the value row; nothing ever waits on these ----
    f32x4* vrow = value4 + ((size_t)blockIdx.x << 11);     // 2048 float4 / row
#pragma unroll
    for (int it = 0; it < 8; ++it) {
        int j = (it << 4) | jg;
        vrow[(j << 4) | c] = t[it];                        // coalesced dwordx4
    }

    // Finish wave: LN(value)-score + q + k + bias, leaky, softmax over 128 j.
    if (threadIdx.x < 64) {
        int lane = threadIdx.x;
        float g = gamma[lane], bt = beta[lane], wv = attw[2 * DIM + lane];
        float Sg = wave_reduce_sum(g * wv);                // sum(gamma*wv)
        float Sb = wave_reduce_sum(bt * wv);               // sum(beta*wv)
        float qi = q_ws[b * N_TOK + i] + attb[0];

        float2 p0 = s12v[lane];
        float2 p1 = s12v[lane + 64];
        float s30 = s3a[lane], s31 = s3a[lane + 64];
        float kj0 = k_ws[b * N_TOK + lane];
        float kj1 = k_ws[b * N_TOK + lane + 64];

        float mu0  = p0.x * (1.f / 64.f);
        float var0 = p0.y * (1.f / 64.f) - mu0 * mu0;
        float sc0  = qi + kj0 + rsqrtf(var0 + LN_EPS) * (s30 - mu0 * Sg) + Sb;
        sc0 = sc0 >= 0.f ? sc0 : SLOPE * sc0;

        float mu1  = p1.x * (1.f / 64.f);
        float var1 = p1.y * (1.f / 64.f) - mu1 * mu1;
        float sc1  = qi + kj1 + rsqrtf(var1 + LN_EPS) * (s31 - mu1 * Sg) + Sb;
        sc1 = sc1 >= 0.f ? sc1 : SLOPE * sc1;

        float m  = wave_reduce_max(fmaxf(sc0, sc1));
        float e0 = __expf(sc0 - m), e1 = __expf(sc1 - m);
        float s  = wave_reduce_sum(e0 + e1);
        float inv = 1.f / s;
        float* arow = alphas + ((size_t)blockIdx.x << 7);
        arow[lane]      = e0 * inv;
        arow[lane + 64] = e1 * inv;
    }
}

extern "C" void kernel_launch(void* const* d_in, const int* in_sizes, int n_in,
                              void* d_out, int out_size, void* d_ws, size_t ws_size,
                              hipStream_t stream) {
    const float* emb   = (const float*)d_in[0];
    const float* gamma = (const float*)d_in[1];
    const float* beta  = (const float*)d_in[2];
    const float* attw  = (const float*)d_in[3];
    const float* attb  = (const float*)d_in[4];
    float* out = (float*)d_out;

    int B = in_sizes[0] / (N_TOK * DIM);     // 32
    int nrows = B * N_TOK;                   // 4096
    float* q_ws = (float*)d_ws;
    float* k_ws = q_ws + nrows;

    float* alphas = out;                             // B*N*N floats
    float* value  = out + (size_t)nrows * N_TOK;     // B*N*N*D floats

    k0_row_stats<<<dim3((nrows + 3) / 4), dim3(256), 0, stream>>>(
        emb, gamma, beta, attw, q_ws, k_ws, nrows);
    k12_fused<<<dim3(nrows), dim3(256), 0, stream>>>(
        emb, gamma, beta, attw, attb, q_ws, k_ws, alphas, (f32x4*)value);
}